// Round 9
// baseline (566.119 us; speedup 1.0000x reference)
//
#include <hip/hip_runtime.h>
#include <stdint.h>

#define T_DIM 512
#define B_DIM 128
#define I_DIM 1024
#define N_DIM 1024
#define NB (N_DIM * B_DIM)     // 131072
#define ROWB 4096              // bytes per combined row: I * (hi+lo f16) = 4 KB

#define DECAY 0.9f
#define THRESH 1.0f

typedef _Float16 f16;
typedef _Float16 f16x8 __attribute__((ext_vector_type(8)));
typedef float f32x16 __attribute__((ext_vector_type(16)));

// -------------------------------------------------------------------------
// Split fp32 -> combined f16 hi/lo layout: dst[row][kc=0..127][hl][8 f16].
// -------------------------------------------------------------------------
__global__ __launch_bounds__(256) void split_w_kernel(
    const float* __restrict__ W, f16* __restrict__ Ws)
{
    int gid = blockIdx.x * 256 + threadIdx.x;       // N*I/8 kchunks
    int kc  = gid & 127;
    int row = gid >> 7;
    const float* src = W + (size_t)row * I_DIM + kc * 8;
    f16* dst = Ws + (size_t)row * 2048 + kc * 16;
    float v[8];
    *(float4*)&v[0] = *(const float4*)src;
    *(float4*)&v[4] = *(const float4*)(src + 4);
    f16 hi[8], lo[8];
    #pragma unroll
    for (int j = 0; j < 8; ++j) {
        hi[j] = (f16)v[j];
        lo[j] = (f16)(v[j] - (float)hi[j]);
    }
    *(f16x8*)dst       = *(const f16x8*)hi;
    *(f16x8*)(dst + 8) = *(const f16x8*)lo;
}

// X chunk: rows indexed [t'][b] (t-major)
__global__ __launch_bounds__(256) void split_x_kernel(
    const float* __restrict__ X, f16* __restrict__ Xc, int t0)
{
    int gid = blockIdx.x * 256 + threadIdx.x;       // tc*128*128 kchunks
    int kc = gid & 127;
    int b  = (gid >> 7) & 127;
    int tp = gid >> 14;
    const float* src = X + ((size_t)b * T_DIM + (t0 + tp)) * I_DIM + kc * 8;
    f16* dst = Xc + ((size_t)tp * 128 + b) * 2048 + kc * 16;
    float v[8];
    *(float4*)&v[0] = *(const float4*)src;
    *(float4*)&v[4] = *(const float4*)(src + 4);
    f16 hi[8], lo[8];
    #pragma unroll
    for (int j = 0; j < 8; ++j) {
        hi[j] = (f16)v[j];
        lo[j] = (f16)(v[j] - (float)hi[j]);
    }
    *(f16x8*)dst       = *(const f16x8*)hi;
    *(f16x8*)(dst + 8) = *(const f16x8*)lo;
}

// -------------------------------------------------------------------------
// GEMM via fp16-split 3xMFMA using 32x32x16 (2382 vs 2075 TF ceiling).
// Round-3 structure verbatim otherwise: 128n x 128b tile / block / t,
// 4 waves (64x64 each), BK=32, 2 x 32KB LDS dbuf, 2 blocks/CU,
// ONE __syncthreads per K-step, stage of tile kt+1 in flight across
// the whole compute phase of tile kt.
// Wave tile = 2x2 fragments of 32x32; per K32: 16 ds_read_b128, 24 MFMA.
// -------------------------------------------------------------------------
__global__ __launch_bounds__(256, 2) void spk_gemm_kernel(
    const uint8_t* __restrict__ Wsb,   // combined W  [N][kc][hl][8]
    const uint8_t* __restrict__ Xcb,   // combined Xc [t'*128+b][kc][hl][8]
    float* __restrict__ C, int tc)
{
    __shared__ __align__(16) uint8_t lds[65536];   // 2 x (A 16K | B 16K)

    const int tid  = threadIdx.x;
    const int wave = tid >> 6, lane = tid & 63;

    // bijective chunked XCD swizzle: same-t blocks colocate on one XCD
    const int nwg = gridDim.x;
    const int q = nwg >> 3, r = nwg & 7;
    const int xcd = blockIdx.x & 7, idx = blockIdx.x >> 3;
    const int wg = (xcd < r ? xcd * (q + 1) : r * (q + 1) + (xcd - r) * q) + idx;
    const int n0 = (wg & 7) << 7;
    const int tp = wg >> 3;

    // staging: 8 granules (16B) per thread; LDS dest linear (granule G*16),
    // source granule XOR-swizzled within each 128B row-chunk.
    const uint8_t* srcp[8];
    #pragma unroll
    for (int c = 0; c < 8; ++c) {
        int Gall = (wave * 8 + c) * 64 + lane;
        int G  = Gall & 1023;
        int rr = G >> 3, gg = G & 7;
        int xofs = ((gg ^ (rr & 7)) << 4);
        if (Gall < 1024)
            srcp[c] = Wsb + (size_t)(n0 + rr) * ROWB + xofs;
        else
            srcp[c] = Xcb + ((size_t)tp * 128 + rr) * ROWB + xofs;
    }

    // fragment offsets: 32x32x16 layout — row/col = lane&31, k-octet = lane>>5
    const int wr = ((wave >> 1) << 6);   // n-offset 0/64
    const int wc = ((wave & 1) << 6);    // b-offset 0/64
    const int l31 = lane & 31, ko = lane >> 5;
    int aoff[2][2][2], boff[2][2][2];    // [m][kh][hl]
    #pragma unroll
    for (int m = 0; m < 2; ++m)
        #pragma unroll
        for (int kh = 0; kh < 2; ++kh)
            #pragma unroll
            for (int hl = 0; hl < 2; ++hl) {
                int g  = 4 * kh + 2 * ko + hl;     // granule within 128B tile-row
                int ra = wr + m * 32 + l31;
                aoff[m][kh][hl] = ra * 128 + ((g ^ (ra & 7)) << 4);
                int rb = wc + m * 32 + l31;
                boff[m][kh][hl] = 16384 + rb * 128 + ((g ^ (rb & 7)) << 4);
            }

    f32x16 acc[2][2];
    #pragma unroll
    for (int m = 0; m < 2; ++m)
        #pragma unroll
        for (int n = 0; n < 2; ++n)
            #pragma unroll
            for (int j = 0; j < 16; ++j) acc[m][n][j] = 0.0f;

    // prologue: stage tile 0 into buffer 0
    #pragma unroll
    for (int c = 0; c < 8; ++c)
        __builtin_amdgcn_global_load_lds(
            (const __attribute__((address_space(1))) uint8_t*)srcp[c],
            (__attribute__((address_space(3))) uint8_t*)&lds[(wave * 8 + c) << 10],
            16, 0, 0);

    int cur = 0;
    for (int ks = 0; ks < 32; ++ks) {
        __syncthreads();   // drains vmcnt(0): buf[cur] ready; WAR-safe for stage below

        // stage NEXT K-step into the other buffer (in flight across the MFMAs)
        if (ks + 1 < 32) {
            const int nb = (cur ^ 1) << 15;
            #pragma unroll
            for (int c = 0; c < 8; ++c)
                __builtin_amdgcn_global_load_lds(
                    (const __attribute__((address_space(1))) uint8_t*)(srcp[c] + (ks + 1) * 128),
                    (__attribute__((address_space(3))) uint8_t*)&lds[nb + ((wave * 8 + c) << 10)],
                    16, 0, 0);
        }

        const uint8_t* bp = &lds[cur << 15];
        #pragma unroll
        for (int kh = 0; kh < 2; ++kh) {
            f16x8 Ah[2], Al[2], Bh[2], Bl[2];
            #pragma unroll
            for (int m = 0; m < 2; ++m) {
                Ah[m] = *(const f16x8*)&bp[aoff[m][kh][0]];
                Al[m] = *(const f16x8*)&bp[aoff[m][kh][1]];
                Bh[m] = *(const f16x8*)&bp[boff[m][kh][0]];
                Bl[m] = *(const f16x8*)&bp[boff[m][kh][1]];
            }
            // 12 MFMA term-outer: 4 independent ops between acc reuses
            #pragma unroll
            for (int m = 0; m < 2; ++m)
                #pragma unroll
                for (int n = 0; n < 2; ++n)
                    acc[m][n] = __builtin_amdgcn_mfma_f32_32x32x16_f16(Ah[m], Bh[n], acc[m][n], 0, 0, 0);
            #pragma unroll
            for (int m = 0; m < 2; ++m)
                #pragma unroll
                for (int n = 0; n < 2; ++n)
                    acc[m][n] = __builtin_amdgcn_mfma_f32_32x32x16_f16(Ah[m], Bl[n], acc[m][n], 0, 0, 0);
            #pragma unroll
            for (int m = 0; m < 2; ++m)
                #pragma unroll
                for (int n = 0; n < 2; ++n)
                    acc[m][n] = __builtin_amdgcn_mfma_f32_32x32x16_f16(Al[m], Bh[n], acc[m][n], 0, 0, 0);
        }
        cur ^= 1;
    }

    // epilogue: C[t'][n][b]
    // 32x32 C/D map: col = lane&31, row = (reg&3) + 8*(reg>>2) + 4*(lane>>5)
    float* cp = C + (size_t)tp * NB;
    #pragma unroll
    for (int m = 0; m < 2; ++m) {
        #pragma unroll
        for (int n = 0; n < 2; ++n) {
            int col = wc + n * 32 + l31;
            #pragma unroll
            for (int reg = 0; reg < 16; ++reg) {
                int row = n0 + wr + m * 32 + (reg & 3) + 8 * (reg >> 2) + 4 * ko;
                cp[(size_t)row * B_DIM + col] = acc[m][n][reg];
            }
        }
    }
}

// -------------------------------------------------------------------------
// Sequential LIF scan per (n,b); state carried across chunk launches.
// -------------------------------------------------------------------------
__global__ __launch_bounds__(256) void spk_scan_kernel(
    const float* __restrict__ cur,   // [tc, NB]
    float* __restrict__ mp_state,    // [NB]
    float* __restrict__ out,         // [NB]
    int tc, int first)
{
    const int nb = blockIdx.x * 256 + threadIdx.x;
    float mp, cnt;
    if (first) { mp = 0.0f; cnt = 0.0f; }
    else       { mp = mp_state[nb]; cnt = out[nb]; }

    const float* p = cur + nb;
    #pragma unroll 8
    for (int t = 0; t < tc; ++t) {
        float c = p[(size_t)t * NB];
        mp = __fadd_rn(__fmul_rn(DECAY, mp), c);
        if (mp >= THRESH) { cnt += 1.0f; mp = 0.0f; }
    }
    mp_state[nb] = mp;
    out[nb] = cnt;
}

extern "C" void kernel_launch(void* const* d_in, const int* in_sizes, int n_in,
                              void* d_out, int out_size, void* d_ws, size_t ws_size,
                              hipStream_t stream) {
    const float* x = (const float*)d_in[0];   // [B, T, I]
    const float* w = (const float*)d_in[1];   // [N, I]
    float* out = (float*)d_out;               // [N, B]

    uint8_t* ws = (uint8_t*)d_ws;
    float* mp  = (float*)ws;                                 // 512 KB
    f16*   Wsp = (f16*)(ws + 524288);                        // 4 MB combined W
    uint8_t* rest = ws + 524288 + 4194304;
    size_t rem = ws_size - 524288 - 4194304;

    // per-t footprint: Xc row block 512KB + cur 512KB = 1 MB
    int Tc = (int)(rem / (size_t)(128 * ROWB + NB * 4));
    if (Tc > T_DIM) Tc = T_DIM;
    if (Tc < 1) Tc = 1;

    f16*   Xcp = (f16*)rest;                                 // Tc * 512 KB
    float* cur = (float*)(rest + (size_t)Tc * 128 * ROWB);   // Tc * 512 KB

    split_w_kernel<<<(N_DIM * I_DIM / 8) / 256, 256, 0, stream>>>(w, Wsp);

    int first = 1;
    for (int t0 = 0; t0 < T_DIM; ) {
        int tc = T_DIM - t0;
        if (tc > Tc) tc = Tc;

        split_x_kernel<<<tc * 64, 256, 0, stream>>>(x, Xcp, t0);
        spk_gemm_kernel<<<tc * 8, 256, 0, stream>>>(
            (const uint8_t*)Wsp, (const uint8_t*)Xcp, cur, tc);
        spk_scan_kernel<<<NB / 256, 256, 0, stream>>>(cur, mp, out, tc, first);

        first = 0;
        t0 += tc;
    }
}

// Round 10
// 548.710 us; speedup vs baseline: 1.0317x; 1.0317x over previous
//
#include <hip/hip_runtime.h>
#include <stdint.h>

#define T_DIM 512
#define B_DIM 128
#define I_DIM 1024
#define N_DIM 1024
#define NB (N_DIM * B_DIM)     // 131072
#define ROWB 4096              // bytes per combined row: I * (hi+lo f16) = 4 KB

#define DECAY 0.9f
#define THRESH 1.0f

typedef _Float16 f16;
typedef _Float16 f16x8 __attribute__((ext_vector_type(8)));
typedef float f32x4 __attribute__((ext_vector_type(4)));

// -------------------------------------------------------------------------
// Split fp32 -> combined f16 hi/lo layout: dst[row][kc=0..127][hl][8 f16].
// -------------------------------------------------------------------------
__global__ __launch_bounds__(256) void split_w_kernel(
    const float* __restrict__ W, f16* __restrict__ Ws)
{
    int gid = blockIdx.x * 256 + threadIdx.x;       // N*I/8 kchunks
    int kc  = gid & 127;
    int row = gid >> 7;
    const float* src = W + (size_t)row * I_DIM + kc * 8;
    f16* dst = Ws + (size_t)row * 2048 + kc * 16;
    float v[8];
    *(float4*)&v[0] = *(const float4*)src;
    *(float4*)&v[4] = *(const float4*)(src + 4);
    f16 hi[8], lo[8];
    #pragma unroll
    for (int j = 0; j < 8; ++j) {
        hi[j] = (f16)v[j];
        lo[j] = (f16)(v[j] - (float)hi[j]);
    }
    *(f16x8*)dst       = *(const f16x8*)hi;
    *(f16x8*)(dst + 8) = *(const f16x8*)lo;
}

// X chunk: rows indexed [t'][b] (t-major)
__global__ __launch_bounds__(256) void split_x_kernel(
    const float* __restrict__ X, f16* __restrict__ Xc, int t0)
{
    int gid = blockIdx.x * 256 + threadIdx.x;       // tc*128*128 kchunks
    int kc = gid & 127;
    int b  = (gid >> 7) & 127;
    int tp = gid >> 14;
    const float* src = X + ((size_t)b * T_DIM + (t0 + tp)) * I_DIM + kc * 8;
    f16* dst = Xc + ((size_t)tp * 128 + b) * 2048 + kc * 16;
    float v[8];
    *(float4*)&v[0] = *(const float4*)src;
    *(float4*)&v[4] = *(const float4*)(src + 4);
    f16 hi[8], lo[8];
    #pragma unroll
    for (int j = 0; j < 8; ++j) {
        hi[j] = (f16)v[j];
        lo[j] = (f16)(v[j] - (float)hi[j]);
    }
    *(f16x8*)dst       = *(const f16x8*)hi;
    *(f16x8*)(dst + 8) = *(const f16x8*)lo;
}

// -------------------------------------------------------------------------
// GEMM via fp16-split 3xMFMA (round-3 structure): 128n x 128b tile / block
// per t, 4 waves (64x64 each), BK=32, 2 x 32KB LDS dbuf, 2 blocks/CU,
// ONE __syncthreads per K-step, stage of tile kt+1 in flight across the
// whole compute phase of tile kt.
// XCD mapping: blocks land on XCD (blockIdx.x % 8) round-robin [m09], so
// n0 = (bid&7)*128 pins ONE 512KB W-panel per XCD -> W stays L2-resident
// for all t; X per-t row-blocks are shared across XCDs via L3.
// -------------------------------------------------------------------------
__global__ __launch_bounds__(256, 2) void spk_gemm_kernel(
    const uint8_t* __restrict__ Wsb,   // combined W  [N][kc][hl][8]
    const uint8_t* __restrict__ Xcb,   // combined Xc [t'*128+b][kc][hl][8]
    float* __restrict__ C, int tc)
{
    __shared__ __align__(16) uint8_t lds[65536];   // 2 x (A 16K | B 16K)

    const int tid  = threadIdx.x;
    const int wave = tid >> 6, lane = tid & 63;

    // n-panel pinned per XCD; t advances within an XCD
    const int n0 = (blockIdx.x & 7) << 7;
    const int tp = blockIdx.x >> 3;

    // staging: 8 granules (16B) per thread; LDS dest linear (granule G*16),
    // source granule XOR-swizzled within each 128B row-chunk.
    const uint8_t* srcp[8];
    #pragma unroll
    for (int c = 0; c < 8; ++c) {
        int Gall = (wave * 8 + c) * 64 + lane;
        int G  = Gall & 1023;
        int rr = G >> 3, gg = G & 7;
        int xofs = ((gg ^ (rr & 7)) << 4);
        if (Gall < 1024)
            srcp[c] = Wsb + (size_t)(n0 + rr) * ROWB + xofs;
        else
            srcp[c] = Xcb + ((size_t)tp * 128 + rr) * ROWB + xofs;
    }

    // fragment LDS byte offsets within a buffer (constant across K-steps)
    const int wr = ((wave >> 1) << 6);   // n-offset 0/64
    const int wc = ((wave & 1) << 6);    // b-offset 0/64
    const int l15 = lane & 15, kcg = lane >> 4, l7 = l15 & 7;
    int aoffH[4], aoffL[4], boffH[4], boffL[4];
    #pragma unroll
    for (int m = 0; m < 4; ++m) {
        int ra = wr + m * 16 + l15;
        aoffH[m] = ra * 128 + ((((kcg << 1) | 0) ^ l7) << 4);
        aoffL[m] = ra * 128 + ((((kcg << 1) | 1) ^ l7) << 4);
        int rb = wc + m * 16 + l15;
        boffH[m] = 16384 + rb * 128 + ((((kcg << 1) | 0) ^ l7) << 4);
        boffL[m] = 16384 + rb * 128 + ((((kcg << 1) | 1) ^ l7) << 4);
    }

    f32x4 acc[4][4];
    #pragma unroll
    for (int m = 0; m < 4; ++m)
        #pragma unroll
        for (int n = 0; n < 4; ++n) acc[m][n] = (f32x4){0.f, 0.f, 0.f, 0.f};

    // prologue: stage tile 0 into buffer 0
    #pragma unroll
    for (int c = 0; c < 8; ++c)
        __builtin_amdgcn_global_load_lds(
            (const __attribute__((address_space(1))) uint8_t*)srcp[c],
            (__attribute__((address_space(3))) uint8_t*)&lds[(wave * 8 + c) << 10],
            16, 0, 0);

    int cur = 0;
    for (int ks = 0; ks < 32; ++ks) {
        __syncthreads();   // drains vmcnt(0): buf[cur] ready; WAR-safe for stage below

        // stage NEXT K-step into the other buffer (in flight across the MFMAs)
        if (ks + 1 < 32) {
            const int nb = (cur ^ 1) << 15;
            #pragma unroll
            for (int c = 0; c < 8; ++c)
                __builtin_amdgcn_global_load_lds(
                    (const __attribute__((address_space(1))) uint8_t*)(srcp[c] + (ks + 1) * 128),
                    (__attribute__((address_space(3))) uint8_t*)&lds[nb + ((wave * 8 + c) << 10)],
                    16, 0, 0);
        }

        const uint8_t* bp = &lds[cur << 15];
        f16x8 Ah[4], Al[4], Bh[4], Bl[4];
        #pragma unroll
        for (int m = 0; m < 4; ++m) {
            Ah[m] = *(const f16x8*)&bp[aoffH[m]];
            Al[m] = *(const f16x8*)&bp[aoffL[m]];
        }
        #pragma unroll
        for (int n = 0; n < 4; ++n) {
            Bh[n] = *(const f16x8*)&bp[boffH[n]];
            Bl[n] = *(const f16x8*)&bp[boffL[n]];
        }
        // 48 MFMAs, term-outer: 16 independent ops between acc reuses
        #pragma unroll
        for (int m = 0; m < 4; ++m)
            #pragma unroll
            for (int n = 0; n < 4; ++n)
                acc[m][n] = __builtin_amdgcn_mfma_f32_16x16x32_f16(Ah[m], Bh[n], acc[m][n], 0, 0, 0);
        #pragma unroll
        for (int m = 0; m < 4; ++m)
            #pragma unroll
            for (int n = 0; n < 4; ++n)
                acc[m][n] = __builtin_amdgcn_mfma_f32_16x16x32_f16(Ah[m], Bl[n], acc[m][n], 0, 0, 0);
        #pragma unroll
        for (int m = 0; m < 4; ++m)
            #pragma unroll
            for (int n = 0; n < 4; ++n)
                acc[m][n] = __builtin_amdgcn_mfma_f32_16x16x32_f16(Al[m], Bh[n], acc[m][n], 0, 0, 0);
        cur ^= 1;
    }

    // epilogue: C[t'][n][b]; C/D map col=lane&15, row=(lane>>4)*4+j
    float* cp = C + (size_t)tp * NB;
    const int rg = (lane >> 4) << 2;
    #pragma unroll
    for (int m = 0; m < 4; ++m) {
        int nrow = n0 + wr + m * 16 + rg;
        #pragma unroll
        for (int n = 0; n < 4; ++n) {
            int col = wc + n * 16 + l15;
            #pragma unroll
            for (int j = 0; j < 4; ++j)
                cp[(size_t)(nrow + j) * B_DIM + col] = acc[m][n][j];
        }
    }
}

// -------------------------------------------------------------------------
// Sequential LIF scan per (n,b); state carried across chunk launches.
// -------------------------------------------------------------------------
__global__ __launch_bounds__(256) void spk_scan_kernel(
    const float* __restrict__ cur,   // [tc, NB]
    float* __restrict__ mp_state,    // [NB]
    float* __restrict__ out,         // [NB]
    int tc, int first)
{
    const int nb = blockIdx.x * 256 + threadIdx.x;
    float mp, cnt;
    if (first) { mp = 0.0f; cnt = 0.0f; }
    else       { mp = mp_state[nb]; cnt = out[nb]; }

    const float* p = cur + nb;
    #pragma unroll 8
    for (int t = 0; t < tc; ++t) {
        float c = p[(size_t)t * NB];
        mp = __fadd_rn(__fmul_rn(DECAY, mp), c);
        if (mp >= THRESH) { cnt += 1.0f; mp = 0.0f; }
    }
    mp_state[nb] = mp;
    out[nb] = cnt;
}

extern "C" void kernel_launch(void* const* d_in, const int* in_sizes, int n_in,
                              void* d_out, int out_size, void* d_ws, size_t ws_size,
                              hipStream_t stream) {
    const float* x = (const float*)d_in[0];   // [B, T, I]
    const float* w = (const float*)d_in[1];   // [N, I]
    float* out = (float*)d_out;               // [N, B]

    uint8_t* ws = (uint8_t*)d_ws;
    float* mp  = (float*)ws;                                 // 512 KB
    f16*   Wsp = (f16*)(ws + 524288);                        // 4 MB combined W
    uint8_t* rest = ws + 524288 + 4194304;
    size_t rem = ws_size - 524288 - 4194304;

    // per-t footprint: Xc row block 512KB + cur 512KB = 1 MB
    int Tc = (int)(rem / (size_t)(128 * ROWB + NB * 4));
    if (Tc > T_DIM) Tc = T_DIM;
    if (Tc < 1) Tc = 1;

    f16*   Xcp = (f16*)rest;                                 // Tc * 512 KB
    float* cur = (float*)(rest + (size_t)Tc * 128 * ROWB);   // Tc * 512 KB

    split_w_kernel<<<(N_DIM * I_DIM / 8) / 256, 256, 0, stream>>>(w, Wsp);

    int first = 1;
    for (int t0 = 0; t0 < T_DIM; ) {
        int tc = T_DIM - t0;
        if (tc > Tc) tc = Tc;

        split_x_kernel<<<tc * 64, 256, 0, stream>>>(x, Xcp, t0);
        spk_gemm_kernel<<<tc * 8, 256, 0, stream>>>(
            (const uint8_t*)Wsp, (const uint8_t*)Xcp, cur, tc);
        spk_scan_kernel<<<NB / 256, 256, 0, stream>>>(cur, mp, out, tc, first);

        first = 0;
        t0 += tc;
    }
}

// Round 11
// 520.544 us; speedup vs baseline: 1.0876x; 1.0541x over previous
//
#include <hip/hip_runtime.h>
#include <stdint.h>

#define T_DIM 512
#define B_DIM 128
#define I_DIM 1024
#define N_DIM 1024
#define NB (N_DIM * B_DIM)     // 131072
#define ROWB 4096              // bytes per combined row: I * (hi+lo f16) = 4 KB

#define DECAY 0.9f
#define THRESH 1.0f

typedef _Float16 f16;
typedef _Float16 f16x8 __attribute__((ext_vector_type(8)));
typedef float f32x4 __attribute__((ext_vector_type(4)));

#define MFMA16 __builtin_amdgcn_mfma_f32_16x16x32_f16

// -------------------------------------------------------------------------
// Split fp32 -> combined f16 hi/lo layout: dst[row][kc=0..127][hl][8 f16].
// -------------------------------------------------------------------------
__global__ __launch_bounds__(256) void split_w_kernel(
    const float* __restrict__ W, f16* __restrict__ Ws)
{
    int gid = blockIdx.x * 256 + threadIdx.x;       // N*I/8 kchunks
    int kc  = gid & 127;
    int row = gid >> 7;
    const float* src = W + (size_t)row * I_DIM + kc * 8;
    f16* dst = Ws + (size_t)row * 2048 + kc * 16;
    float v[8];
    *(float4*)&v[0] = *(const float4*)src;
    *(float4*)&v[4] = *(const float4*)(src + 4);
    f16 hi[8], lo[8];
    #pragma unroll
    for (int j = 0; j < 8; ++j) {
        hi[j] = (f16)v[j];
        lo[j] = (f16)(v[j] - (float)hi[j]);
    }
    *(f16x8*)dst       = *(const f16x8*)hi;
    *(f16x8*)(dst + 8) = *(const f16x8*)lo;
}

// X chunk: rows indexed [t'][b] (t-major)
__global__ __launch_bounds__(256) void split_x_kernel(
    const float* __restrict__ X, f16* __restrict__ Xc, int t0)
{
    int gid = blockIdx.x * 256 + threadIdx.x;       // tc*128*128 kchunks
    int kc = gid & 127;
    int b  = (gid >> 7) & 127;
    int tp = gid >> 14;
    const float* src = X + ((size_t)b * T_DIM + (t0 + tp)) * I_DIM + kc * 8;
    f16* dst = Xc + ((size_t)tp * 128 + b) * 2048 + kc * 16;
    float v[8];
    *(float4*)&v[0] = *(const float4*)src;
    *(float4*)&v[4] = *(const float4*)(src + 4);
    f16 hi[8], lo[8];
    #pragma unroll
    for (int j = 0; j < 8; ++j) {
        hi[j] = (f16)v[j];
        lo[j] = (f16)(v[j] - (float)hi[j]);
    }
    *(f16x8*)dst       = *(const f16x8*)hi;
    *(f16x8*)(dst + 8) = *(const f16x8*)lo;
}

// -------------------------------------------------------------------------
// GEMM via fp16-split 3xMFMA — m201-style 8-wave fine-phase schedule.
// Block = 256n x 256col (col = (t',b), 2 t per block). 8 waves, wave tile
// 128n x 64col. BK=32, LDS = 2 x (A 32K | B 32K) = 128 KB, 1 block/CU.
// Per K-tile: 4 phases {stage 2 G-loads of tile kt+1 | ds_read m-pair
// (+ all B in ph0) -> s_barrier -> lgkmcnt(0) -> 24 term-outer MFMA ->
// s_barrier}; vmcnt(2) ONCE per tile (next tile's 8 loads in flight
// across all 4 phases). B-frags live in registers across phases.
// -------------------------------------------------------------------------
__global__ __launch_bounds__(512, 2) void spk_gemm_kernel(
    const uint8_t* __restrict__ Wsb,   // combined W  [N][kc][hl][8]
    const uint8_t* __restrict__ Xcb,   // combined Xc [t'*128+b][kc][hl][8]
    float* __restrict__ C, int tc)
{
    __shared__ __align__(16) uint8_t lds[131072];  // 2 x (A 32K | B 32K)

    const int tid  = threadIdx.x;
    const int wave = tid >> 6, lane = tid & 63;
    const int wbase16 = wave << 10;                // wave*1024 (stage dest)

    // bid%8 -> XCD [m09]; n-panel = (bid&7)>>1 pins a 1MB W-panel per XCD;
    // colblk panels are shared by 4 XCDs via L3.
    const int bid = blockIdx.x;
    const int n0     = ((bid & 7) >> 1) << 8;          // 0,256,512,768
    const int colblk = ((bid >> 3) << 1) | (bid & 1);  // 0 .. tc/2-1

    // staging sources: 4 A-granules + 4 B-granules per thread (16B each),
    // inverse-XOR swizzled within each 128B row-chunk; LDS dest linear.
    const uint8_t* srcA[4];
    const uint8_t* srcB[4];
    #pragma unroll
    for (int c = 0; c < 4; ++c) {
        int G = c * 512 + tid;          // 0..2047
        int rr = G >> 3, gg = G & 7;    // row 0..255, slot
        int xofs = ((gg ^ (rr & 7)) << 4);
        srcA[c] = Wsb + (size_t)(n0 + rr) * ROWB + xofs;
        srcB[c] = Xcb + ((size_t)colblk * 256 + rr) * ROWB + xofs;
    }

    // fragment LDS byte offsets within a buffer
    const int wrb = (wave >> 2) << 7;   // n-offset 0/128
    const int wcb = (wave & 3) << 6;    // col-offset 0/64/128/192
    const int l15 = lane & 15, kcg = lane >> 4, l7 = l15 & 7;
    int aoff[8][2], boff[4][2];
    #pragma unroll
    for (int m = 0; m < 8; ++m) {
        int ra = wrb + m * 16 + l15;    // ra&7 == l7
        aoff[m][0] = ra * 128 + ((((kcg << 1) | 0) ^ l7) << 4);
        aoff[m][1] = ra * 128 + ((((kcg << 1) | 1) ^ l7) << 4);
    }
    #pragma unroll
    for (int nf = 0; nf < 4; ++nf) {
        int rb = wcb + nf * 16 + l15;
        boff[nf][0] = 32768 + rb * 128 + ((((kcg << 1) | 0) ^ l7) << 4);
        boff[nf][1] = 32768 + rb * 128 + ((((kcg << 1) | 1) ^ l7) << 4);
    }

    f32x4 acc[8][4];
    #pragma unroll
    for (int m = 0; m < 8; ++m)
        #pragma unroll
        for (int n = 0; n < 4; ++n) acc[m][n] = (f32x4){0.f, 0.f, 0.f, 0.f};

#define STAGE2(KT, C_) do {                                                   \
    const int qb_ = (((KT) & 1) << 16);                                       \
    __builtin_amdgcn_global_load_lds(                                         \
        (const __attribute__((address_space(1))) uint8_t*)(srcA[C_] + (KT) * 128), \
        (__attribute__((address_space(3))) uint8_t*)&lds[qb_ + (C_) * 8192 + wbase16], \
        16, 0, 0);                                                            \
    __builtin_amdgcn_global_load_lds(                                         \
        (const __attribute__((address_space(1))) uint8_t*)(srcB[C_] + (KT) * 128), \
        (__attribute__((address_space(3))) uint8_t*)&lds[qb_ + 32768 + (C_) * 8192 + wbase16], \
        16, 0, 0);                                                            \
} while (0)

// Phase P of tile KT. DOSTAGE: issue 2 G-loads of tile KT+1 (chunk P).
// DOVM (P==0 only): vmcnt(#VMC) + barrier = tile-KT residency gate.
#define PHASE(KT, P, DOSTAGE, DOVM, VMC) do {                                 \
    if (DOSTAGE) STAGE2((KT) + 1, P);                                         \
    if (DOVM) {                                                               \
        asm volatile("s_waitcnt vmcnt(" #VMC ")" ::: "memory");               \
        __builtin_amdgcn_s_barrier();                                         \
    }                                                                         \
    const uint8_t* bp_ = &lds[(((KT) & 1) << 16)];                            \
    f16x8 Ah0_ = *(const f16x8*)&bp_[aoff[2 * (P)][0]];                       \
    f16x8 Al0_ = *(const f16x8*)&bp_[aoff[2 * (P)][1]];                       \
    f16x8 Ah1_ = *(const f16x8*)&bp_[aoff[2 * (P) + 1][0]];                   \
    f16x8 Al1_ = *(const f16x8*)&bp_[aoff[2 * (P) + 1][1]];                   \
    if ((P) == 0) {                                                           \
        _Pragma("unroll")                                                     \
        for (int nf_ = 0; nf_ < 4; ++nf_) {                                   \
            Bh[nf_] = *(const f16x8*)&bp_[boff[nf_][0]];                      \
            Bl[nf_] = *(const f16x8*)&bp_[boff[nf_][1]];                      \
        }                                                                     \
    }                                                                         \
    asm volatile("s_waitcnt lgkmcnt(0)" ::: "memory");                        \
    __builtin_amdgcn_sched_barrier(0);                                        \
    __builtin_amdgcn_s_setprio(1);                                            \
    _Pragma("unroll")                                                         \
    for (int nf_ = 0; nf_ < 4; ++nf_)                                         \
        acc[2 * (P)][nf_]     = MFMA16(Ah0_, Bh[nf_], acc[2 * (P)][nf_], 0, 0, 0); \
    _Pragma("unroll")                                                         \
    for (int nf_ = 0; nf_ < 4; ++nf_)                                         \
        acc[2 * (P) + 1][nf_] = MFMA16(Ah1_, Bh[nf_], acc[2 * (P) + 1][nf_], 0, 0, 0); \
    _Pragma("unroll")                                                         \
    for (int nf_ = 0; nf_ < 4; ++nf_)                                         \
        acc[2 * (P)][nf_]     = MFMA16(Ah0_, Bl[nf_], acc[2 * (P)][nf_], 0, 0, 0); \
    _Pragma("unroll")                                                         \
    for (int nf_ = 0; nf_ < 4; ++nf_)                                         \
        acc[2 * (P) + 1][nf_] = MFMA16(Ah1_, Bl[nf_], acc[2 * (P) + 1][nf_], 0, 0, 0); \
    _Pragma("unroll")                                                         \
    for (int nf_ = 0; nf_ < 4; ++nf_)                                         \
        acc[2 * (P)][nf_]     = MFMA16(Al0_, Bh[nf_], acc[2 * (P)][nf_], 0, 0, 0); \
    _Pragma("unroll")                                                         \
    for (int nf_ = 0; nf_ < 4; ++nf_)                                         \
        acc[2 * (P) + 1][nf_] = MFMA16(Al1_, Bh[nf_], acc[2 * (P) + 1][nf_], 0, 0, 0); \
    __builtin_amdgcn_s_setprio(0);                                            \
    __builtin_amdgcn_s_barrier();                                             \
} while (0)

    // prologue: stage all of tile 0 into buffer 0
    #pragma unroll
    for (int c = 0; c < 4; ++c) STAGE2(0, c);

    f16x8 Bh[4], Bl[4];
    // steady state entering tile kt ph0: outstanding = 8 (tile kt) + 2 just
    // issued (tile kt+1 chunk 0) -> vmcnt(2) == tile kt fully resident.
    for (int kt = 0; kt < 31; ++kt) {
        PHASE(kt, 0, 1, 1, 2);
        PHASE(kt, 1, 1, 0, 0);
        PHASE(kt, 2, 1, 0, 0);
        PHASE(kt, 3, 1, 0, 0);
    }
    PHASE(31, 0, 0, 1, 0);
    PHASE(31, 1, 0, 0, 0);
    PHASE(31, 2, 0, 0, 0);
    PHASE(31, 3, 0, 0, 0);

    // epilogue: col = wcb + nf*16 + l15 -> t' = colblk*2 + (wcb>>7), b = col&127
    // C/D map: col(lane&15), row = (lane>>4)*4 + j
    float* cp = C + (size_t)(colblk * 2 + (wcb >> 7)) * NB;
    const int rg = (lane >> 4) << 2;
    const int bb = wcb & 127;
    #pragma unroll
    for (int m = 0; m < 8; ++m) {
        int nrow = n0 + wrb + m * 16 + rg;
        #pragma unroll
        for (int nf = 0; nf < 4; ++nf) {
            int col = bb + nf * 16 + l15;
            #pragma unroll
            for (int j = 0; j < 4; ++j)
                cp[(size_t)(nrow + j) * B_DIM + col] = acc[m][nf][j];
        }
    }
}

// -------------------------------------------------------------------------
// Sequential LIF scan per (n,b); state carried across chunk launches.
// -------------------------------------------------------------------------
__global__ __launch_bounds__(256) void spk_scan_kernel(
    const float* __restrict__ cur,   // [tc, NB]
    float* __restrict__ mp_state,    // [NB]
    float* __restrict__ out,         // [NB]
    int tc, int first)
{
    const int nb = blockIdx.x * 256 + threadIdx.x;
    float mp, cnt;
    if (first) { mp = 0.0f; cnt = 0.0f; }
    else       { mp = mp_state[nb]; cnt = out[nb]; }

    const float* p = cur + nb;
    #pragma unroll 8
    for (int t = 0; t < tc; ++t) {
        float c = p[(size_t)t * NB];
        mp = __fadd_rn(__fmul_rn(DECAY, mp), c);
        if (mp >= THRESH) { cnt += 1.0f; mp = 0.0f; }
    }
    mp_state[nb] = mp;
    out[nb] = cnt;
}

extern "C" void kernel_launch(void* const* d_in, const int* in_sizes, int n_in,
                              void* d_out, int out_size, void* d_ws, size_t ws_size,
                              hipStream_t stream) {
    const float* x = (const float*)d_in[0];   // [B, T, I]
    const float* w = (const float*)d_in[1];   // [N, I]
    float* out = (float*)d_out;               // [N, B]

    uint8_t* ws = (uint8_t*)d_ws;
    float* mp  = (float*)ws;                                 // 512 KB
    f16*   Wsp = (f16*)(ws + 524288);                        // 4 MB combined W
    uint8_t* rest = ws + 524288 + 4194304;
    size_t rem = ws_size - 524288 - 4194304;

    // per-t footprint: Xc row block 512KB + cur 512KB = 1 MB; Tc even.
    int Tc = (int)(rem / (size_t)(128 * ROWB + NB * 4));
    if (Tc > T_DIM) Tc = T_DIM;
    Tc &= ~1;
    if (Tc < 2) Tc = 2;

    f16*   Xcp = (f16*)rest;                                 // Tc * 512 KB
    float* cur = (float*)(rest + (size_t)Tc * 128 * ROWB);   // Tc * 512 KB

    split_w_kernel<<<(N_DIM * I_DIM / 8) / 256, 256, 0, stream>>>(w, Wsp);

    int first = 1;
    for (int t0 = 0; t0 < T_DIM; ) {
        int tc = T_DIM - t0;
        if (tc > Tc) tc = Tc;

        split_x_kernel<<<tc * 64, 256, 0, stream>>>(x, Xcp, t0);
        spk_gemm_kernel<<<(tc / 2) * 4, 512, 0, stream>>>(
            (const uint8_t*)Wsp, (const uint8_t*)Xcp, cur, tc);
        spk_scan_kernel<<<NB / 256, 256, 0, stream>>>(cur, mp, out, tc, first);

        first = 0;
        t0 += tc;
    }
}